// Round 5
// baseline (347.241 us; speedup 1.0000x reference)
//
#include <hip/hip_runtime.h>

typedef unsigned short u16;
typedef unsigned int u32;
typedef __bf16 bf16x8 __attribute__((ext_vector_type(8)));
typedef short s16x4 __attribute__((ext_vector_type(4)));
typedef float f32x4 __attribute__((ext_vector_type(4)));

#define MFMA16(a,b,c) __builtin_amdgcn_mfma_f32_16x16x32_bf16((a),(b),(c),0,0,0)

// K=16 bf16 MFMA (v_mfma_f32_16x16x16_bf16): A/B = 4 bf16 (2 VGPR), C/D = 4 f32.
#if defined(__has_builtin)
#if __has_builtin(__builtin_amdgcn_mfma_f32_16x16x16bf16_1k)
#define MFMA1K(a,b,c) __builtin_amdgcn_mfma_f32_16x16x16bf16_1k((a),(b),(c),0,0,0)
#endif
#endif
#ifndef MFMA1K
__device__ __forceinline__ f32x4 mfma1k_asm(s16x4 a, s16x4 b, f32x4 c) {
    f32x4 d;
    asm volatile("v_mfma_f32_16x16x16_bf16 %0, %1, %2, %3"
                 : "=v"(d) : "v"(a), "v"(b), "0"(c));
    return d;
}
#define MFMA1K(a,b,c) mfma1k_asm((a),(b),(c))
#endif

__device__ __forceinline__ float b2f(u16 u) {
    u32 v = ((u32)u) << 16;
    return __builtin_bit_cast(float, v);
}
__device__ __forceinline__ u16 f2b(float f) {
    u32 u = __builtin_bit_cast(u32, f);
    u = u + 0x7FFFu + ((u >> 16) & 1u);   // RNE
    return (u16)(u >> 16);
}

// async global->LDS, 16B per lane. LDS dest is wave-uniform base + lane*16.
__device__ __forceinline__ void gload_lds16(const u16* g, u16* l) {
    __builtin_amdgcn_global_load_lds(
        (__attribute__((address_space(1))) void*)g,
        (__attribute__((address_space(3))) void*)l, 16, 0, 0);
}

// load 8 contiguous elements at element-offset `off`, as 8 bf16 (uint4).
__device__ __forceinline__ uint4 load8_bf16(const void* base, size_t off, int f32m) {
    if (f32m) {
        const float* p = (const float*)base + off;
        float4 a = *(const float4*)p;
        float4 b = *(const float4*)(p + 4);
        union { u16 u[8]; uint4 v; } t;
        t.u[0] = f2b(a.x); t.u[1] = f2b(a.y); t.u[2] = f2b(a.z); t.u[3] = f2b(a.w);
        t.u[4] = f2b(b.x); t.u[5] = f2b(b.y); t.u[6] = f2b(b.z); t.u[7] = f2b(b.w);
        return t.v;
    }
    return *(const uint4*)((const u16*)base + off);
}

// ---- dtype detector: even-indexed u16s of f32 data are random mantissa bits
__global__ __launch_bounds__(256) void k_detect(const u16* __restrict__ x, int* flag) {
    __shared__ int c;
    if (threadIdx.x == 0) c = 0;
    __syncthreads();
    int my = 0;
    #pragma unroll
    for (int j = 0; j < 16; ++j) {
        u16 v = x[2 * (threadIdx.x + 256 * j)];
        if (((v >> 7) & 0xFF) >= 0x90) ++my;
    }
    atomicAdd(&c, my);
    __syncthreads();
    if (threadIdx.x == 0) *flag = (c > 64) ? 1 : 0;
}

__global__ __launch_bounds__(256) void k_cvt_bias(
    const void* __restrict__ ba, const void* __restrict__ bp,
    const int* __restrict__ flag, u16* __restrict__ bac, u16* __restrict__ bpc)
{
    const int f32m = *flag;
    const int t = threadIdx.x;
    #pragma unroll
    for (int j = 0; j < 12; ++j) {
        int i = t + 256 * j;
        if (i < 3072) bac[i] = f32m ? f2b(((const float*)ba)[i]) : ((const u16*)ba)[i];
    }
    #pragma unroll
    for (int j = 0; j < 4; ++j) {
        int i = t + 256 * j;
        if (i < 1024) bpc[i] = f32m ? f2b(((const float*)bp)[i]) : ((const u16*)bp)[i];
    }
}

// ---- one-time x f32->bf16 conversion (f32 mode only; bf16 mode uses x directly)
__global__ __launch_bounds__(256) void k_cvt_x(
    const float* __restrict__ x, const int* __restrict__ flag, u16* __restrict__ out)
{
    if (!*flag) return;
    size_t i = ((size_t)blockIdx.x * 256 + threadIdx.x) * 8;
    float4 a = *(const float4*)(x + i);
    float4 b = *(const float4*)(x + i + 4);
    union { u16 u[8]; uint4 v; } t;
    t.u[0] = f2b(a.x); t.u[1] = f2b(a.y); t.u[2] = f2b(a.z); t.u[3] = f2b(a.w);
    t.u[4] = f2b(b.x); t.u[5] = f2b(b.y); t.u[6] = f2b(b.z); t.u[7] = f2b(b.w);
    *(uint4*)(out + i) = t.v;
}

// ---------------- transpose+convert: src[R][Cc] -> dst[Cc][R] bf16 ---------
__global__ __launch_bounds__(256) void k_transpose(
    const void* __restrict__ src, u16* __restrict__ dst, int R, int Cc,
    const int* __restrict__ flag)
{
    __shared__ u16 tile[64 * 72];
    const int f32m = *flag;
    const int t = threadIdx.x;
    const int c0 = blockIdx.x * 64, r0 = blockIdx.y * 64;
    #pragma unroll
    for (int i = 0; i < 2; ++i) {
        int ch = t + 256 * i;            // 512 chunks of 8
        int r = ch >> 3, c8 = (ch & 7) * 8;
        *(uint4*)&tile[r * 72 + c8] =
            load8_bf16(src, (size_t)(r0 + r) * Cc + c0 + c8, f32m);
    }
    __syncthreads();
    #pragma unroll
    for (int i = 0; i < 2; ++i) {
        int ch = t + 256 * i;
        int r = ch >> 3, c8 = (ch & 7) * 8;
        union { u16 u[8]; uint4 v; } tmp;
        #pragma unroll
        for (int j = 0; j < 8; ++j) tmp.u[j] = tile[(c8 + j) * 72 + r];
        *(uint4*)&dst[(size_t)(c0 + r) * R + r0 + c8] = tmp.v;
    }
}

// ---------------- QKV GEMM: A[8192,1024] x Bt[3072,1024]^T + bias ----------
// m97 structure: linear [128][64] bf16 LDS tiles, global_load_lds width-16
// staging, 2 barriers per K-step.
__global__ __launch_bounds__(256) void k_gemm_qkv(
    const void* __restrict__ x, const u16* __restrict__ Abf,
    const u16* __restrict__ Bt, const u16* __restrict__ bias,
    const int* __restrict__ flag,
    u16* __restrict__ Ql, u16* __restrict__ Kl, u16* __restrict__ Vt)
{
    constexpr int K = 1024;
    __shared__ __align__(16) u16 As[128 * 64];
    __shared__ __align__(16) u16 Bs[128 * 64];
    const int t = threadIdx.x;
    const int lane = t & 63, w = t >> 6;
    const int quad = lane >> 4, m16 = lane & 15;
    const int wm = (w >> 1) * 64, wn = (w & 1) * 64;
    const int m0 = blockIdx.x * 128, n0 = blockIdx.y * 128;
    const int lr = lane >> 3;            // row within 8-row chunk
    const int lc = (lane & 7) * 8;       // elem col within 64
    const u16* A = (*flag) ? Abf : (const u16*)x;

    const f32x4 z = {0.f, 0.f, 0.f, 0.f};
    f32x4 acc[4][4];
    #pragma unroll
    for (int mi = 0; mi < 4; ++mi)
        #pragma unroll
        for (int ni = 0; ni < 4; ++ni) acc[mi][ni] = z;

    for (int k0 = 0; k0 < K; k0 += 64) {
        __syncthreads();                 // previous compute done reading LDS
        #pragma unroll
        for (int i = 0; i < 4; ++i) {
            const int chunk = w * 4 + i;               // wave-uniform
            const int row = chunk * 8 + lr;
            gload_lds16(&A [(size_t)(m0 + row) * K + k0 + lc], &As[chunk * 512]);
            gload_lds16(&Bt[(size_t)(n0 + row) * K + k0 + lc], &Bs[chunk * 512]);
        }
        __syncthreads();                 // compiler drains vmcnt(0) here
        #pragma unroll
        for (int kk = 0; kk < 2; ++kk) {
            bf16x8 af[4], bfr[4];
            #pragma unroll
            for (int mi = 0; mi < 4; ++mi)
                af[mi] = *(const bf16x8*)&As[(wm + mi * 16 + m16) * 64 + kk * 32 + quad * 8];
            #pragma unroll
            for (int ni = 0; ni < 4; ++ni)
                bfr[ni] = *(const bf16x8*)&Bs[(wn + ni * 16 + m16) * 64 + kk * 32 + quad * 8];
            #pragma unroll
            for (int mi = 0; mi < 4; ++mi)
                #pragma unroll
                for (int ni = 0; ni < 4; ++ni)
                    acc[mi][ni] = MFMA16(af[mi], bfr[ni], acc[mi][ni]);
        }
    }

    const int sec = n0 >> 10;  // 0=Q,1=K,2=V — uniform per block (128 | 1024)
    const float qscale = (sec == 0) ? 0.18033688011112042f : 1.0f;  // 0.125*log2e
    #pragma unroll
    for (int mi = 0; mi < 4; ++mi) {
        #pragma unroll
        for (int ni = 0; ni < 4; ++ni) {
            int gn = n0 + wn + ni * 16 + m16;
            int sn = gn & 1023;
            int h = sn >> 6, d = sn & 63;
            float bv = b2f(bias[gn]);
            #pragma unroll
            for (int v = 0; v < 4; ++v) {
                int gm = m0 + wm + mi * 16 + quad * 4 + v;
                int bb = gm >> 11, tt = gm & 2047;
                u16 o = f2b((acc[mi][ni][v] + bv) * qscale);
                size_t bh = (size_t)(bb * 16 + h);
                if (sec == 0)      Ql[(bh * 2048 + tt) * 64 + d] = o;
                else if (sec == 1) Kl[(bh * 2048 + tt) * 64 + d] = o;
                else               Vt[(bh * 64 + d) * 2048 + tt] = o;
            }
        }
    }
}

// ---------------- flash attention: block = (256 q rows, one (b,h)) ---------
// QBLK=256 / 8 waves: evidence from rounds 1/3/4 shows k_attn is bound by
// L2<->LLC fill traffic from K/V re-reads (dur == hbm_bytes / 2.47 TB/s in
// all three rounds, insensitive to LDS/VALU/MFMA changes). Doubling QBLK
// halves the number of q-blocks reading each K/V tile -> logical fill
// traffic per head: 136 tiles -> 72 tiles.
// Per-wave structure identical to round 4 (2 strips x 16 rows; swapped QK^T
// -> register-resident P as B-fragment of v_mfma_f32_16x16x16_bf16).
// Grid: 512 blocks = exactly 2/CU resident; qb remap pairs long+short
// blocks on each CU ({16+2,14+4,12+6,10+8} tiles = 18/CU uniform).
// Strip-level causal skip removes fully-masked (strip, tile) pairs.
__global__ __launch_bounds__(512) void k_attn(
    u16* __restrict__ Ql, const u16* __restrict__ Kl, const u16* __restrict__ Vt)
{
    __shared__ u16 Ks[128 * 80];
    __shared__ u16 Vs[64 * 136];
    const int t = threadIdx.x;
    const int lane = t & 63, w = t >> 6;       // w = 0..7
    const int quad = lane >> 4, m16 = lane & 15;
    const int g = blockIdx.x >> 6;
    const int qb = (g < 4) ? (7 - g) : (g - 4);   // load-balanced pairing
    const int bh = blockIdx.x & 63;               // XCD = bh % 8
    const int q0 = qb * 256;

    // Q fragments for both strips (rows q0 + (w*2+s)*16 + m16)
    bf16x8 fq[2][2];
    #pragma unroll
    for (int s = 0; s < 2; ++s) {
        const u16* Qp = Ql + ((size_t)bh * 2048 + q0 + (w * 2 + s) * 16 + m16) * 64;
        fq[s][0] = *(const bf16x8*)&Qp[quad * 8];
        fq[s][1] = *(const bf16x8*)&Qp[32 + quad * 8];
    }

    const f32x4 z = {0.f, 0.f, 0.f, 0.f};
    f32x4 acco[2][4] = {{z, z, z, z}, {z, z, z, z}};   // O^T: q=m16, d=nd*16+quad*4+v
    float lsum[2] = {0.f, 0.f};

    const int ktmax = 2 * qb + 1;              // tiles = 2*(qb+1)
    const u16* Kbase = Kl + (size_t)bh * 2048 * 64;
    const u16* Vbase = Vt + (size_t)bh * 64 * 2048;

    uint4 kreg[2], vreg[2];
    #pragma unroll
    for (int i = 0; i < 2; ++i) {
        int c = t + 512 * i;
        int r = c >> 3, col = (c & 7) * 8;
        kreg[i] = *(const uint4*)&Kbase[(size_t)r * 64 + col];          // kt=0
        int dd = c >> 4, kvc = (c & 15) * 8;
        vreg[i] = *(const uint4*)&Vbase[(size_t)dd * 2048 + kvc];       // kt=0
    }

    for (int kt = 0; kt <= ktmax; ++kt) {
        __syncthreads();
        #pragma unroll
        for (int i = 0; i < 2; ++i) {
            int c = t + 512 * i;
            int r = c >> 3, col = (c & 7) * 8;
            *(uint4*)&Ks[r * 80 + col] = kreg[i];
            int dd = c >> 4, kvc = (c & 15) * 8;
            *(uint4*)&Vs[dd * 136 + kvc] = vreg[i];
        }
        __syncthreads();

        if (kt < ktmax) {   // prefetch next tile; overlaps compute
            #pragma unroll
            for (int i = 0; i < 2; ++i) {
                int c = t + 512 * i;
                int r = c >> 3, col = (c & 7) * 8;
                kreg[i] = *(const uint4*)&Kbase[(size_t)((kt + 1) * 128 + r) * 64 + col];
                int dd = c >> 4, kvc = (c & 15) * 8;
                vreg[i] = *(const uint4*)&Vbase[(size_t)dd * 2048 + (kt + 1) * 128 + kvc];
            }
        }

        #pragma unroll
        for (int s = 0; s < 2; ++s) {
            const int qsmin = q0 + (w * 2 + s) * 16;        // strip's lowest q row
            if (kt * 128 > qsmin + 15) continue;            // tile fully masked
            const bool maskt = (kt * 128 + 127 > qsmin);    // tile crosses diagonal

            // S^T = K Q^T  (lane: q = m16, kv = ni*16 + quad*4 + v)
            f32x4 accs[8] = {z, z, z, z, z, z, z, z};
            #pragma unroll
            for (int kk = 0; kk < 2; ++kk)
                #pragma unroll
                for (int ni = 0; ni < 8; ++ni) {
                    bf16x8 bk = *(const bf16x8*)&Ks[(ni * 16 + m16) * 80 + kk * 32 + quad * 8];
                    accs[ni] = MFMA16(bk, fq[s][kk], accs[ni]);
                }

            // p = exp2(s^T): pack to bf16 IN REGISTERS (B-fragment of K=16 mfma)
            const int qg = qsmin + m16;
            s16x4 pkv[8];
            #pragma unroll
            for (int ni = 0; ni < 8; ++ni) {
                union { __bf16 b[4]; s16x4 sv; } pk;
                #pragma unroll
                for (int v = 0; v < 4; ++v) {
                    float sc = accs[ni][v];
                    if (maskt && (kt * 128 + ni * 16 + quad * 4 + v > qg)) sc = -30000.0f;
                    float pe = __builtin_amdgcn_exp2f(sc);
                    pk.b[v] = (__bf16)pe;
                    lsum[s] += pe;
                }
                pkv[ni] = pk.sv;
            }

            // O^T += V^T P^T : A = V^T b64 fragment, B = pkv (register)
            #pragma unroll
            for (int ni = 0; ni < 8; ++ni) {
                #pragma unroll
                for (int nd = 0; nd < 4; ++nd) {
                    s16x4 va = *(const s16x4*)&Vs[(nd * 16 + m16) * 136 + ni * 16 + quad * 4];
                    acco[s][nd] = MFMA1K(va, pkv[ni], acco[s][nd]);
                }
            }
        }
    }

    // l: reduce per-lane partials across the 4 quads (lanes m16 + 16k)
    #pragma unroll
    for (int s = 0; s < 2; ++s) {
        lsum[s] += __shfl_xor(lsum[s], 16);
        lsum[s] += __shfl_xor(lsum[s], 32);
    }

    // write O back into Ql ([bh][t][64]): lane owns row q = qg, 4 consecutive d
    #pragma unroll
    for (int s = 0; s < 2; ++s) {
        const int qg = q0 + (w * 2 + s) * 16 + m16;
        const float inv = 1.0f / fmaxf(lsum[s], 1e-30f);
        u16* Orow = &Ql[((size_t)bh * 2048 + qg) * 64];
        #pragma unroll
        for (int nd = 0; nd < 4; ++nd) {
            union { u16 u[4]; uint2 uu; } o;
            #pragma unroll
            for (int v = 0; v < 4; ++v) o.u[v] = f2b(acco[s][nd][v] * inv);
            *(uint2*)&Orow[nd * 16 + quad * 4] = o.uu;
        }
    }
}

// ------- proj GEMM: Y (in Ql layout [bh][t][64]) x WpT[1024,1024]^T + bias -
__global__ __launch_bounds__(256) void k_gemm_proj(
    const u16* __restrict__ Yl, const u16* __restrict__ Bt, const u16* __restrict__ bias,
    const int* __restrict__ flag, void* __restrict__ Out)
{
    constexpr int K = 1024;
    __shared__ __align__(16) u16 As[128 * 64];
    __shared__ __align__(16) u16 Bs[128 * 64];
    const int f32m = *flag;
    const int t = threadIdx.x;
    const int lane = t & 63, w = t >> 6;
    const int quad = lane >> 4, m16 = lane & 15;
    const int wm = (w >> 1) * 64, wn = (w & 1) * 64;
    const int m0 = blockIdx.x * 128, n0 = blockIdx.y * 128;
    const int bb = m0 >> 11, t0 = m0 & 2047;   // block-uniform (128 | 2048)
    const int lr = lane >> 3;
    const int lc = (lane & 7) * 8;

    const f32x4 z = {0.f, 0.f, 0.f, 0.f};
    f32x4 acc[4][4];
    #pragma unroll
    for (int mi = 0; mi < 4; ++mi)
        #pragma unroll
        for (int ni = 0; ni < 4; ++ni) acc[mi][ni] = z;

    for (int k0 = 0; k0 < K; k0 += 64) {
        const int h = k0 >> 6;
        const u16* Abase = Yl + ((size_t)(bb * 16 + h) * 2048 + t0) * 64;
        __syncthreads();
        #pragma unroll
        for (int i = 0; i < 4; ++i) {
            const int chunk = w * 4 + i;               // wave-uniform
            gload_lds16(&Abase[chunk * 512 + lane * 8], &As[chunk * 512]);
            gload_lds16(&Bt[(size_t)(n0 + chunk * 8 + lr) * K + k0 + lc], &Bs[chunk * 512]);
        }
        __syncthreads();
        #pragma unroll
        for (int kk = 0; kk < 2; ++kk) {
            bf16x8 af[4], bfr[4];
            #pragma unroll
            for (int mi = 0; mi < 4; ++mi)
                af[mi] = *(const bf16x8*)&As[(wm + mi * 16 + m16) * 64 + kk * 32 + quad * 8];
            #pragma unroll
            for (int ni = 0; ni < 4; ++ni)
                bfr[ni] = *(const bf16x8*)&Bs[(wn + ni * 16 + m16) * 64 + kk * 32 + quad * 8];
            #pragma unroll
            for (int mi = 0; mi < 4; ++mi)
                #pragma unroll
                for (int ni = 0; ni < 4; ++ni)
                    acc[mi][ni] = MFMA16(af[mi], bfr[ni], acc[mi][ni]);
        }
    }

    #pragma unroll
    for (int mi = 0; mi < 4; ++mi) {
        #pragma unroll
        for (int ni = 0; ni < 4; ++ni) {
            int gn = n0 + wn + ni * 16 + m16;
            float bv = b2f(bias[gn]);
            #pragma unroll
            for (int v = 0; v < 4; ++v) {
                int gm = m0 + wm + mi * 16 + quad * 4 + v;
                float val = acc[mi][ni][v] + bv;
                if (f32m) ((float*)Out)[(size_t)gm * 1024 + gn] = val;
                else      ((u16*)Out)[(size_t)gm * 1024 + gn] = f2b(val);
            }
        }
    }
}

extern "C" void kernel_launch(void* const* d_in, const int* in_sizes, int n_in,
                              void* d_out, int out_size, void* d_ws, size_t ws_size,
                              hipStream_t stream)
{
    (void)in_sizes; (void)n_in; (void)out_size; (void)ws_size;
    const void* x  = d_in[0];   // [8192,1024]  f32 or bf16
    const void* Wa = d_in[1];   // [1024,3072]
    const void* ba = d_in[2];   // [3072]
    const void* Wp = d_in[3];   // [1024,1024]
    const void* bp = d_in[4];   // [1024]
    char* ws = (char*)d_ws;

    // ws: Q/O 16M @0 | K 16M @16M | V 16M @32M | WpT 2M @48M | flag/bpc/bac @50M
    u16* Ql  = (u16*)(ws + 0);
    u16* Kl  = (u16*)(ws + 16777216);
    u16* Vt  = (u16*)(ws + 33554432);
    u16* WpT = (u16*)(ws + 50331648);
    int* flag = (int*)(ws + 52428800);
    u16* bpc  = (u16*)(ws + 52428800 + 256);
    u16* bac  = (u16*)(ws + 52428800 + 256 + 2048);
    // d_out doubles as scratch until proj:
    //   WaT 6M @0 | Abf (bf16 x) 16M @6M (written only in f32 mode, where
    //   out_size = 33.5M; in bf16 mode Abf is never touched and A = x).
    u16* WaT = (u16*)d_out;
    u16* Abf = (u16*)((char*)d_out + 6291456);

    k_detect<<<1, 256, 0, stream>>>((const u16*)x, flag);
    k_cvt_bias<<<1, 256, 0, stream>>>(ba, bp, flag, bac, bpc);
    k_cvt_x<<<4096, 256, 0, stream>>>((const float*)x, flag, Abf);
    k_transpose<<<dim3(48, 16), 256, 0, stream>>>(Wa, WaT, 1024, 3072, flag);
    k_transpose<<<dim3(16, 16), 256, 0, stream>>>(Wp, WpT, 1024, 1024, flag);
    k_gemm_qkv<<<dim3(64, 24), 256, 0, stream>>>(x, Abf, WaT, bac, flag, Ql, Kl, Vt);
    k_attn<<<512, 512, 0, stream>>>(Ql, Kl, Vt);
    k_gemm_proj<<<dim3(64, 8), 256, 0, stream>>>(Ql, WpT, bpc, flag, d_out);
}

// Round 6
// 297.333 us; speedup vs baseline: 1.1679x; 1.1679x over previous
//
#include <hip/hip_runtime.h>

typedef unsigned short u16;
typedef unsigned int u32;
typedef __bf16 bf16x8 __attribute__((ext_vector_type(8)));
typedef short s16x4 __attribute__((ext_vector_type(4)));
typedef float f32x4 __attribute__((ext_vector_type(4)));

#define MFMA16(a,b,c) __builtin_amdgcn_mfma_f32_16x16x32_bf16((a),(b),(c),0,0,0)

// K=16 bf16 MFMA (v_mfma_f32_16x16x16_bf16): A/B = 4 bf16 (2 VGPR), C/D = 4 f32.
#if defined(__has_builtin)
#if __has_builtin(__builtin_amdgcn_mfma_f32_16x16x16bf16_1k)
#define MFMA1K(a,b,c) __builtin_amdgcn_mfma_f32_16x16x16bf16_1k((a),(b),(c),0,0,0)
#endif
#endif
#ifndef MFMA1K
__device__ __forceinline__ f32x4 mfma1k_asm(s16x4 a, s16x4 b, f32x4 c) {
    f32x4 d;
    asm volatile("v_mfma_f32_16x16x16_bf16 %0, %1, %2, %3"
                 : "=v"(d) : "v"(a), "v"(b), "0"(c));
    return d;
}
#define MFMA1K(a,b,c) mfma1k_asm((a),(b),(c))
#endif

__device__ __forceinline__ float b2f(u16 u) {
    u32 v = ((u32)u) << 16;
    return __builtin_bit_cast(float, v);
}
__device__ __forceinline__ u16 f2b(float f) {
    u32 u = __builtin_bit_cast(u32, f);
    u = u + 0x7FFFu + ((u >> 16) & 1u);   // RNE
    return (u16)(u >> 16);
}

// async global->LDS, 16B per lane. LDS dest is wave-uniform base + lane*16.
__device__ __forceinline__ void gload_lds16(const u16* g, u16* l) {
    __builtin_amdgcn_global_load_lds(
        (__attribute__((address_space(1))) void*)g,
        (__attribute__((address_space(3))) void*)l, 16, 0, 0);
}

// load 8 contiguous elements at element-offset `off`, as 8 bf16 (uint4).
__device__ __forceinline__ uint4 load8_bf16(const void* base, size_t off, int f32m) {
    if (f32m) {
        const float* p = (const float*)base + off;
        float4 a = *(const float4*)p;
        float4 b = *(const float4*)(p + 4);
        union { u16 u[8]; uint4 v; } t;
        t.u[0] = f2b(a.x); t.u[1] = f2b(a.y); t.u[2] = f2b(a.z); t.u[3] = f2b(a.w);
        t.u[4] = f2b(b.x); t.u[5] = f2b(b.y); t.u[6] = f2b(b.z); t.u[7] = f2b(b.w);
        return t.v;
    }
    return *(const uint4*)((const u16*)base + off);
}

// ---- per-block deterministic dtype vote (identical result in every block):
// even-indexed u16s of f32 data are random mantissa bits -> exponent-field
// check >= 0x90 fires ~44% on f32 low-halves, never on bf16 values.
__device__ __forceinline__ int detect_f32(const u16* __restrict__ x) {
    __shared__ int cnt;
    if (threadIdx.x == 0) cnt = 0;
    __syncthreads();
    int my = ((x[2 * (threadIdx.x * 128)] >> 7) & 0xFF) >= 0x90;
    unsigned long long b = __ballot(my);
    if ((threadIdx.x & 63) == 0) atomicAdd(&cnt, (int)__popcll(b));
    __syncthreads();
    return cnt > 32;
}

// ---- transpose+convert tile: src[R][Cc] -> dst[Cc][R] bf16, 64x64 tile ----
__device__ __forceinline__ void transpose_tile(
    const void* __restrict__ src, u16* __restrict__ dst, int R, int Cc,
    int f32m, int bx, int by)
{
    __shared__ u16 tile[64 * 72];
    const int t = threadIdx.x;
    const int c0 = bx * 64, r0 = by * 64;
    #pragma unroll
    for (int i = 0; i < 2; ++i) {
        int ch = t + 256 * i;            // 512 chunks of 8
        int r = ch >> 3, c8 = (ch & 7) * 8;
        *(uint4*)&tile[r * 72 + c8] =
            load8_bf16(src, (size_t)(r0 + r) * Cc + c0 + c8, f32m);
    }
    __syncthreads();
    #pragma unroll
    for (int i = 0; i < 2; ++i) {
        int ch = t + 256 * i;
        int r = ch >> 3, c8 = (ch & 7) * 8;
        union { u16 u[8]; uint4 v; } tmp;
        #pragma unroll
        for (int j = 0; j < 8; ++j) tmp.u[j] = tile[(c8 + j) * 72 + r];
        *(uint4*)&dst[(size_t)(c0 + r) * R + r0 + c8] = tmp.v;
    }
}

// ---- fused preprocessing: one launch replaces detect/cvt_bias/cvt_x/2xtranspose
// task partition: [0,768) Wa-transpose | [768,1024) Wp-transpose |
//                 [1024,5120) cvt_x    | 5120: biases + flag write
__global__ __launch_bounds__(256) void k_prep(
    const u16* __restrict__ x, const void* __restrict__ Wa,
    const void* __restrict__ ba, const void* __restrict__ Wp,
    const void* __restrict__ bp,
    u16* __restrict__ WaT, u16* __restrict__ WpT, u16* __restrict__ Abf,
    u16* __restrict__ bac, u16* __restrict__ bpc, int* __restrict__ flag)
{
    const int f32m = detect_f32(x);
    int task = blockIdx.x;
    if (task < 768) {
        transpose_tile(Wa, WaT, 1024, 3072, f32m, task % 48, task / 48);
        return;
    }
    task -= 768;
    if (task < 256) {
        transpose_tile(Wp, WpT, 1024, 1024, f32m, task % 16, task / 16);
        return;
    }
    task -= 256;
    if (task < 4096) {   // x f32->bf16 (f32 mode only; bf16 mode uses x directly)
        if (!f32m) return;
        size_t i = ((size_t)task * 256 + threadIdx.x) * 8;
        const float* xf = (const float*)x;
        float4 a = *(const float4*)(xf + i);
        float4 b = *(const float4*)(xf + i + 4);
        union { u16 u[8]; uint4 v; } t;
        t.u[0] = f2b(a.x); t.u[1] = f2b(a.y); t.u[2] = f2b(a.z); t.u[3] = f2b(a.w);
        t.u[4] = f2b(b.x); t.u[5] = f2b(b.y); t.u[6] = f2b(b.z); t.u[7] = f2b(b.w);
        *(uint4*)(Abf + i) = t.v;
        return;
    }
    // biases + flag
    const int t = threadIdx.x;
    #pragma unroll
    for (int j = 0; j < 12; ++j) {
        int i = t + 256 * j;
        if (i < 3072) bac[i] = f32m ? f2b(((const float*)ba)[i]) : ((const u16*)ba)[i];
    }
    #pragma unroll
    for (int j = 0; j < 4; ++j) {
        int i = t + 256 * j;
        if (i < 1024) bpc[i] = f32m ? f2b(((const float*)bp)[i]) : ((const u16*)bp)[i];
    }
    if (t == 0) *flag = f32m;
}

// ---------------- QKV GEMM: A[8192,1024] x Bt[3072,1024]^T + bias ----------
// m97 structure: linear [128][64] bf16 LDS tiles, global_load_lds width-16
// staging, 2 barriers per K-step.
// epilogue: Q,K AND V all coalesced [BH][T][64] (V-transpose moved into
// k_attn's LDS staging — the old Vt scatter was 16 stores/thread at 4KB
// stride, ~8.4M isolated 2B transactions through L2).
__global__ __launch_bounds__(256) void k_gemm_qkv(
    const void* __restrict__ x, const u16* __restrict__ Abf,
    const u16* __restrict__ Bt, const u16* __restrict__ bias,
    const int* __restrict__ flag,
    u16* __restrict__ Ql, u16* __restrict__ Kl, u16* __restrict__ Vl)
{
    constexpr int K = 1024;
    __shared__ __align__(16) u16 As[128 * 64];
    __shared__ __align__(16) u16 Bs[128 * 64];
    const int t = threadIdx.x;
    const int lane = t & 63, w = t >> 6;
    const int quad = lane >> 4, m16 = lane & 15;
    const int wm = (w >> 1) * 64, wn = (w & 1) * 64;
    const int m0 = blockIdx.x * 128, n0 = blockIdx.y * 128;
    const int lr = lane >> 3;            // row within 8-row chunk
    const int lc = (lane & 7) * 8;       // elem col within 64
    const u16* A = (*flag) ? Abf : (const u16*)x;

    const f32x4 z = {0.f, 0.f, 0.f, 0.f};
    f32x4 acc[4][4];
    #pragma unroll
    for (int mi = 0; mi < 4; ++mi)
        #pragma unroll
        for (int ni = 0; ni < 4; ++ni) acc[mi][ni] = z;

    for (int k0 = 0; k0 < K; k0 += 64) {
        __syncthreads();                 // previous compute done reading LDS
        #pragma unroll
        for (int i = 0; i < 4; ++i) {
            const int chunk = w * 4 + i;               // wave-uniform
            const int row = chunk * 8 + lr;
            gload_lds16(&A [(size_t)(m0 + row) * K + k0 + lc], &As[chunk * 512]);
            gload_lds16(&Bt[(size_t)(n0 + row) * K + k0 + lc], &Bs[chunk * 512]);
        }
        __syncthreads();                 // compiler drains vmcnt(0) here
        #pragma unroll
        for (int kk = 0; kk < 2; ++kk) {
            bf16x8 af[4], bfr[4];
            #pragma unroll
            for (int mi = 0; mi < 4; ++mi)
                af[mi] = *(const bf16x8*)&As[(wm + mi * 16 + m16) * 64 + kk * 32 + quad * 8];
            #pragma unroll
            for (int ni = 0; ni < 4; ++ni)
                bfr[ni] = *(const bf16x8*)&Bs[(wn + ni * 16 + m16) * 64 + kk * 32 + quad * 8];
            #pragma unroll
            for (int mi = 0; mi < 4; ++mi)
                #pragma unroll
                for (int ni = 0; ni < 4; ++ni)
                    acc[mi][ni] = MFMA16(af[mi], bfr[ni], acc[mi][ni]);
        }
    }

    const int sec = n0 >> 10;  // 0=Q,1=K,2=V — uniform per block (128 | 1024)
    const float qscale = (sec == 0) ? 0.18033688011112042f : 1.0f;  // 0.125*log2e
    u16* Outp = (sec == 0) ? Ql : (sec == 1) ? Kl : Vl;
    #pragma unroll
    for (int mi = 0; mi < 4; ++mi) {
        #pragma unroll
        for (int ni = 0; ni < 4; ++ni) {
            int gn = n0 + wn + ni * 16 + m16;
            int sn = gn & 1023;
            int h = sn >> 6, d = sn & 63;
            float bv = b2f(bias[gn]);
            #pragma unroll
            for (int v = 0; v < 4; ++v) {
                int gm = m0 + wm + mi * 16 + quad * 4 + v;
                int bb = gm >> 11, tt = gm & 2047;
                u16 o = f2b((acc[mi][ni][v] + bv) * qscale);
                size_t bh = (size_t)(bb * 16 + h);
                Outp[(bh * 2048 + tt) * 64 + d] = o;
            }
        }
    }
}

// ---------------- flash attention: block = (128 q rows, one (b,h)) ---------
// Round-4 structure (best measured: 117 us) with:
//  * V read ROW-major [bh][t][64] from global (coalesced); the d<->kv
//    transpose happens in the LDS staging write (8x ds_write_b16/thread,
//    Vs stride 132 -> ~4-way on writes, b64-aligned reads).
//  * explicit diag/non-diag softmax paths: non-diagonal tiles (88%) skip
//    the per-element causal cndmask chain entirely (VALU is the busiest
//    pipe: 35% in round 4).
// Swapped QK^T -> register-resident P as B-fragment of mfma 16x16x16.
// Strips sequential, V from LDS (round-2 lesson: stay under 128 VGPR).
__global__ __launch_bounds__(256) void k_attn(
    u16* __restrict__ Ql, const u16* __restrict__ Kl, const u16* __restrict__ Vl)
{
    __shared__ u16 Ks[128 * 80];
    __shared__ u16 Vs[64 * 132];
    const int t = threadIdx.x;
    const int lane = t & 63, w = t >> 6;
    const int quad = lane >> 4, m16 = lane & 15;
    const int qb = 15 - (blockIdx.x >> 6);     // LPT: longest first
    const int bh = blockIdx.x & 63;            // XCD affinity (64 % 8 == 0)
    const int q0 = qb * 128;

    // Q fragments for both strips, registers for the whole block
    bf16x8 fq[2][2];
    #pragma unroll
    for (int s = 0; s < 2; ++s) {
        const u16* Qp = Ql + ((size_t)bh * 2048 + q0 + s * 64 + w * 16 + m16) * 64;
        fq[s][0] = *(const bf16x8*)&Qp[quad * 8];
        fq[s][1] = *(const bf16x8*)&Qp[32 + quad * 8];
    }

    const f32x4 z = {0.f, 0.f, 0.f, 0.f};
    f32x4 acco[2][4] = {{z, z, z, z}, {z, z, z, z}};   // O^T: q=m16, d=nd*16+quad*4+v
    float lsum[2] = {0.f, 0.f};

    const int ktmax = qb;
    const u16* Kbase = Kl + (size_t)bh * 2048 * 64;
    const u16* Vbase = Vl + (size_t)bh * 2048 * 64;

    uint4 kreg[4], vreg[4];
    #pragma unroll
    for (int i = 0; i < 4; ++i) {
        int c = t + 256 * i;
        int r = c >> 3, col = (c & 7) * 8;
        kreg[i] = *(const uint4*)&Kbase[(size_t)r * 64 + col];          // kt=0
        vreg[i] = *(const uint4*)&Vbase[(size_t)r * 64 + col];          // kt=0
    }

    for (int kt = 0; kt <= ktmax; ++kt) {
        __syncthreads();
        #pragma unroll
        for (int i = 0; i < 4; ++i) {
            int c = t + 256 * i;
            int r = c >> 3, col = (c & 7) * 8;   // r = row (kv), col = d0
            *(uint4*)&Ks[r * 80 + col] = kreg[i];
            union { u16 u[8]; uint4 v; } tv; tv.v = vreg[i];
            #pragma unroll
            for (int j = 0; j < 8; ++j)          // transpose into Vs[d][kv]
                Vs[(col + j) * 132 + r] = tv.u[j];
        }
        __syncthreads();

        if (kt < ktmax) {   // prefetch next tile; overlaps compute
            #pragma unroll
            for (int i = 0; i < 4; ++i) {
                int c = t + 256 * i;
                int r = c >> 3, col = (c & 7) * 8;
                kreg[i] = *(const uint4*)&Kbase[(size_t)((kt + 1) * 128 + r) * 64 + col];
                vreg[i] = *(const uint4*)&Vbase[(size_t)((kt + 1) * 128 + r) * 64 + col];
            }
        }

        const bool diag = (kt == ktmax);
        #pragma unroll
        for (int s = 0; s < 2; ++s) {
            // S^T = K Q^T  (lane: q = m16, kv = ni*16 + quad*4 + v)
            f32x4 accs[8] = {z, z, z, z, z, z, z, z};
            #pragma unroll
            for (int kk = 0; kk < 2; ++kk)
                #pragma unroll
                for (int ni = 0; ni < 8; ++ni) {
                    bf16x8 bk = *(const bf16x8*)&Ks[(ni * 16 + m16) * 80 + kk * 32 + quad * 8];
                    accs[ni] = MFMA16(bk, fq[s][kk], accs[ni]);
                }

            // p = exp2(s^T): pack to bf16 IN REGISTERS (B-fragment of K=16 mfma)
            s16x4 pkv[8];
            if (!diag) {
                #pragma unroll
                for (int ni = 0; ni < 8; ++ni) {
                    union { __bf16 b[4]; s16x4 sv; } pk;
                    #pragma unroll
                    for (int v = 0; v < 4; ++v) {
                        float pe = __builtin_amdgcn_exp2f(accs[ni][v]);
                        pk.b[v] = (__bf16)pe;
                        lsum[s] += pe;
                    }
                    pkv[ni] = pk.sv;
                }
            } else {
                const int qg = q0 + s * 64 + w * 16 + m16;
                #pragma unroll
                for (int ni = 0; ni < 8; ++ni) {
                    union { __bf16 b[4]; s16x4 sv; } pk;
                    #pragma unroll
                    for (int v = 0; v < 4; ++v) {
                        float sc = accs[ni][v];
                        if (kt * 128 + ni * 16 + quad * 4 + v > qg) sc = -30000.0f;
                        float pe = __builtin_amdgcn_exp2f(sc);
                        pk.b[v] = (__bf16)pe;
                        lsum[s] += pe;
                    }
                    pkv[ni] = pk.sv;
                }
            }

            // O^T += V^T P^T : A = V^T b64 fragment, B = pkv (register)
            #pragma unroll
            for (int ni = 0; ni < 8; ++ni) {
                #pragma unroll
                for (int nd = 0; nd < 4; ++nd) {
                    s16x4 va = *(const s16x4*)&Vs[(nd * 16 + m16) * 132 + ni * 16 + quad * 4];
                    acco[s][nd] = MFMA1K(va, pkv[ni], acco[s][nd]);
                }
            }
        }
    }

    // l: reduce per-lane partials across the 4 quads (lanes m16 + 16k)
    #pragma unroll
    for (int s = 0; s < 2; ++s) {
        lsum[s] += __shfl_xor(lsum[s], 16);
        lsum[s] += __shfl_xor(lsum[s], 32);
    }

    // write O back into Ql ([bh][t][64]): lane owns row q = qg, 4 consecutive d
    #pragma unroll
    for (int s = 0; s < 2; ++s) {
        const int qg = q0 + s * 64 + w * 16 + m16;
        const float inv = 1.0f / fmaxf(lsum[s], 1e-30f);
        u16* Orow = &Ql[((size_t)bh * 2048 + qg) * 64];
        #pragma unroll
        for (int nd = 0; nd < 4; ++nd) {
            union { u16 u[4]; uint2 uu; } o;
            #pragma unroll
            for (int v = 0; v < 4; ++v) o.u[v] = f2b(acco[s][nd][v] * inv);
            *(uint2*)&Orow[nd * 16 + quad * 4] = o.uu;
        }
    }
}

// ------- proj GEMM: Y (in Ql layout [bh][t][64]) x WpT[1024,1024]^T + bias -
__global__ __launch_bounds__(256) void k_gemm_proj(
    const u16* __restrict__ Yl, const u16* __restrict__ Bt, const u16* __restrict__ bias,
    const int* __restrict__ flag, void* __restrict__ Out)
{
    constexpr int K = 1024;
    __shared__ __align__(16) u16 As[128 * 64];
    __shared__ __align__(16) u16 Bs[128 * 64];
    const int f32m = *flag;
    const int t = threadIdx.x;
    const int lane = t & 63, w = t >> 6;
    const int quad = lane >> 4, m16 = lane & 15;
    const int wm = (w >> 1) * 64, wn = (w & 1) * 64;
    const int m0 = blockIdx.x * 128, n0 = blockIdx.y * 128;
    const int bb = m0 >> 11, t0 = m0 & 2047;   // block-uniform (128 | 2048)
    const int lr = lane >> 3;
    const int lc = (lane & 7) * 8;

    const f32x4 z = {0.f, 0.f, 0.f, 0.f};
    f32x4 acc[4][4];
    #pragma unroll
    for (int mi = 0; mi < 4; ++mi)
        #pragma unroll
        for (int ni = 0; ni < 4; ++ni) acc[mi][ni] = z;

    for (int k0 = 0; k0 < K; k0 += 64) {
        const int h = k0 >> 6;
        const u16* Abase = Yl + ((size_t)(bb * 16 + h) * 2048 + t0) * 64;
        __syncthreads();
        #pragma unroll
        for (int i = 0; i < 4; ++i) {
            const int chunk = w * 4 + i;               // wave-uniform
            gload_lds16(&Abase[chunk * 512 + lane * 8], &As[chunk * 512]);
            gload_lds16(&Bt[(size_t)(n0 + chunk * 8 + lr) * K + k0 + lc], &Bs[chunk * 512]);
        }
        __syncthreads();
        #pragma unroll
        for (int kk = 0; kk < 2; ++kk) {
            bf16x8 af[4], bfr[4];
            #pragma unroll
            for (int mi = 0; mi < 4; ++mi)
                af[mi] = *(const bf16x8*)&As[(wm + mi * 16 + m16) * 64 + kk * 32 + quad * 8];
            #pragma unroll
            for (int ni = 0; ni < 4; ++ni)
                bfr[ni] = *(const bf16x8*)&Bs[(wn + ni * 16 + m16) * 64 + kk * 32 + quad * 8];
            #pragma unroll
            for (int mi = 0; mi < 4; ++mi)
                #pragma unroll
                for (int ni = 0; ni < 4; ++ni)
                    acc[mi][ni] = MFMA16(af[mi], bfr[ni], acc[mi][ni]);
        }
    }

    #pragma unroll
    for (int mi = 0; mi < 4; ++mi) {
        #pragma unroll
        for (int ni = 0; ni < 4; ++ni) {
            int gn = n0 + wn + ni * 16 + m16;
            float bv = b2f(bias[gn]);
            #pragma unroll
            for (int v = 0; v < 4; ++v) {
                int gm = m0 + wm + mi * 16 + quad * 4 + v;
                float val = acc[mi][ni][v] + bv;
                if (f32m) ((float*)Out)[(size_t)gm * 1024 + gn] = val;
                else      ((u16*)Out)[(size_t)gm * 1024 + gn] = f2b(val);
            }
        }
    }
}

extern "C" void kernel_launch(void* const* d_in, const int* in_sizes, int n_in,
                              void* d_out, int out_size, void* d_ws, size_t ws_size,
                              hipStream_t stream)
{
    (void)in_sizes; (void)n_in; (void)out_size; (void)ws_size;
    const void* x  = d_in[0];   // [8192,1024]  f32 or bf16
    const void* Wa = d_in[1];   // [1024,3072]
    const void* ba = d_in[2];   // [3072]
    const void* Wp = d_in[3];   // [1024,1024]
    const void* bp = d_in[4];   // [1024]
    char* ws = (char*)d_ws;

    // ws: Q/O 16M @0 | K 16M @16M | V(row-major) 16M @32M | WpT 2M @48M | misc @50M
    u16* Ql  = (u16*)(ws + 0);
    u16* Kl  = (u16*)(ws + 16777216);
    u16* Vl  = (u16*)(ws + 33554432);
    u16* WpT = (u16*)(ws + 50331648);
    int* flag = (int*)(ws + 52428800);
    u16* bpc  = (u16*)(ws + 52428800 + 256);
    u16* bac  = (u16*)(ws + 52428800 + 256 + 2048);
    // d_out doubles as scratch until proj:
    //   WaT 6M @0 | Abf (bf16 x) 16M @6M (written only in f32 mode, where
    //   out_size = 33.5M; in bf16 mode Abf is never touched and A = x).
    u16* WaT = (u16*)d_out;
    u16* Abf = (u16*)((char*)d_out + 6291456);

    k_prep<<<5121, 256, 0, stream>>>((const u16*)x, Wa, ba, Wp, bp,
                                     WaT, WpT, Abf, bac, bpc, flag);
    k_gemm_qkv<<<dim3(64, 24), 256, 0, stream>>>(x, Abf, WaT, bac, flag, Ql, Kl, Vl);
    k_attn<<<1024, 256, 0, stream>>>(Ql, Kl, Vl);
    k_gemm_proj<<<dim3(64, 8), 256, 0, stream>>>(Ql, WpT, bpc, flag, d_out);
}

// Round 7
// 289.050 us; speedup vs baseline: 1.2013x; 1.0287x over previous
//
#include <hip/hip_runtime.h>

typedef unsigned short u16;
typedef unsigned int u32;
typedef __bf16 bf16x8 __attribute__((ext_vector_type(8)));
typedef short s16x4 __attribute__((ext_vector_type(4)));
typedef float f32x4 __attribute__((ext_vector_type(4)));

#define MFMA16(a,b,c) __builtin_amdgcn_mfma_f32_16x16x32_bf16((a),(b),(c),0,0,0)

// K=16 bf16 MFMA (v_mfma_f32_16x16x16_bf16): A/B = 4 bf16 (2 VGPR), C/D = 4 f32.
#if defined(__has_builtin)
#if __has_builtin(__builtin_amdgcn_mfma_f32_16x16x16bf16_1k)
#define MFMA1K(a,b,c) __builtin_amdgcn_mfma_f32_16x16x16bf16_1k((a),(b),(c),0,0,0)
#endif
#endif
#ifndef MFMA1K
__device__ __forceinline__ f32x4 mfma1k_asm(s16x4 a, s16x4 b, f32x4 c) {
    f32x4 d;
    asm volatile("v_mfma_f32_16x16x16_bf16 %0, %1, %2, %3"
                 : "=v"(d) : "v"(a), "v"(b), "0"(c));
    return d;
}
#define MFMA1K(a,b,c) mfma1k_asm((a),(b),(c))
#endif

__device__ __forceinline__ float b2f(u16 u) {
    u32 v = ((u32)u) << 16;
    return __builtin_bit_cast(float, v);
}
__device__ __forceinline__ u16 f2b(float f) {
    u32 u = __builtin_bit_cast(u32, f);
    u = u + 0x7FFFu + ((u >> 16) & 1u);   // RNE
    return (u16)(u >> 16);
}

// async global->LDS, 16B per lane. LDS dest is wave-uniform base + lane*16.
__device__ __forceinline__ void gload_lds16(const u16* g, u16* l) {
    __builtin_amdgcn_global_load_lds(
        (__attribute__((address_space(1))) void*)g,
        (__attribute__((address_space(3))) void*)l, 16, 0, 0);
}

// load 8 contiguous elements at element-offset `off`, as 8 bf16 (uint4).
__device__ __forceinline__ uint4 load8_bf16(const void* base, size_t off, int f32m) {
    if (f32m) {
        const float* p = (const float*)base + off;
        float4 a = *(const float4*)p;
        float4 b = *(const float4*)(p + 4);
        union { u16 u[8]; uint4 v; } t;
        t.u[0] = f2b(a.x); t.u[1] = f2b(a.y); t.u[2] = f2b(a.z); t.u[3] = f2b(a.w);
        t.u[4] = f2b(b.x); t.u[5] = f2b(b.y); t.u[6] = f2b(b.z); t.u[7] = f2b(b.w);
        return t.v;
    }
    return *(const uint4*)((const u16*)base + off);
}

// ---- per-block deterministic dtype vote (identical result in every block):
// even-indexed u16s of f32 data are random mantissa bits -> exponent-field
// check >= 0x90 fires ~44% on f32 low-halves, never on bf16 values.
__device__ __forceinline__ int detect_f32(const u16* __restrict__ x) {
    __shared__ int cnt;
    if (threadIdx.x == 0) cnt = 0;
    __syncthreads();
    int my = ((x[2 * (threadIdx.x * 128)] >> 7) & 0xFF) >= 0x90;
    unsigned long long b = __ballot(my);
    if ((threadIdx.x & 63) == 0) atomicAdd(&cnt, (int)__popcll(b));
    __syncthreads();
    return cnt > 32;
}

// ---- transpose+convert tile: src[R][Cc] -> dst[Cc][R] bf16, 64x64 tile ----
__device__ __forceinline__ void transpose_tile(
    const void* __restrict__ src, u16* __restrict__ dst, int R, int Cc,
    int f32m, int bx, int by)
{
    __shared__ u16 tile[64 * 72];
    const int t = threadIdx.x;
    const int c0 = bx * 64, r0 = by * 64;
    #pragma unroll
    for (int i = 0; i < 2; ++i) {
        int ch = t + 256 * i;            // 512 chunks of 8
        int r = ch >> 3, c8 = (ch & 7) * 8;
        *(uint4*)&tile[r * 72 + c8] =
            load8_bf16(src, (size_t)(r0 + r) * Cc + c0 + c8, f32m);
    }
    __syncthreads();
    #pragma unroll
    for (int i = 0; i < 2; ++i) {
        int ch = t + 256 * i;
        int r = ch >> 3, c8 = (ch & 7) * 8;
        union { u16 u[8]; uint4 v; } tmp;
        #pragma unroll
        for (int j = 0; j < 8; ++j) tmp.u[j] = tile[(c8 + j) * 72 + r];
        *(uint4*)&dst[(size_t)(c0 + r) * R + r0 + c8] = tmp.v;
    }
}

// ---- fused preprocessing: one launch replaces detect/cvt_bias/cvt_x/2xtranspose
// task partition: [0,768) Wa-transpose | [768,1024) Wp-transpose |
//                 [1024,5120) cvt_x    | 5120: biases + flag write
__global__ __launch_bounds__(256) void k_prep(
    const u16* __restrict__ x, const void* __restrict__ Wa,
    const void* __restrict__ ba, const void* __restrict__ Wp,
    const void* __restrict__ bp,
    u16* __restrict__ WaT, u16* __restrict__ WpT, u16* __restrict__ Abf,
    u16* __restrict__ bac, u16* __restrict__ bpc, int* __restrict__ flag)
{
    const int f32m = detect_f32(x);
    int task = blockIdx.x;
    if (task < 768) {
        transpose_tile(Wa, WaT, 1024, 3072, f32m, task % 48, task / 48);
        return;
    }
    task -= 768;
    if (task < 256) {
        transpose_tile(Wp, WpT, 1024, 1024, f32m, task % 16, task / 16);
        return;
    }
    task -= 256;
    if (task < 4096) {   // x f32->bf16 (f32 mode only; bf16 mode uses x directly)
        if (!f32m) return;
        size_t i = ((size_t)task * 256 + threadIdx.x) * 8;
        const float* xf = (const float*)x;
        float4 a = *(const float4*)(xf + i);
        float4 b = *(const float4*)(xf + i + 4);
        union { u16 u[8]; uint4 v; } t;
        t.u[0] = f2b(a.x); t.u[1] = f2b(a.y); t.u[2] = f2b(a.z); t.u[3] = f2b(a.w);
        t.u[4] = f2b(b.x); t.u[5] = f2b(b.y); t.u[6] = f2b(b.z); t.u[7] = f2b(b.w);
        *(uint4*)(Abf + i) = t.v;
        return;
    }
    // biases + flag
    const int t = threadIdx.x;
    #pragma unroll
    for (int j = 0; j < 12; ++j) {
        int i = t + 256 * j;
        if (i < 3072) bac[i] = f32m ? f2b(((const float*)ba)[i]) : ((const u16*)ba)[i];
    }
    #pragma unroll
    for (int j = 0; j < 4; ++j) {
        int i = t + 256 * j;
        if (i < 1024) bpc[i] = f32m ? f2b(((const float*)bp)[i]) : ((const u16*)bp)[i];
    }
    if (t == 0) *flag = f32m;
}

// ---------------- QKV GEMM: A[8192,1024] x Bt[3072,1024]^T + bias ----------
// m97 structure: linear [128][64] bf16 LDS tiles, global_load_lds width-16
// staging, 2 barriers per K-step. Q/K/V epilogues all coalesced [BH][T][64].
__global__ __launch_bounds__(256) void k_gemm_qkv(
    const void* __restrict__ x, const u16* __restrict__ Abf,
    const u16* __restrict__ Bt, const u16* __restrict__ bias,
    const int* __restrict__ flag,
    u16* __restrict__ Ql, u16* __restrict__ Kl, u16* __restrict__ Vl)
{
    constexpr int K = 1024;
    __shared__ __align__(16) u16 As[128 * 64];
    __shared__ __align__(16) u16 Bs[128 * 64];
    const int t = threadIdx.x;
    const int lane = t & 63, w = t >> 6;
    const int quad = lane >> 4, m16 = lane & 15;
    const int wm = (w >> 1) * 64, wn = (w & 1) * 64;
    const int m0 = blockIdx.x * 128, n0 = blockIdx.y * 128;
    const int lr = lane >> 3;            // row within 8-row chunk
    const int lc = (lane & 7) * 8;       // elem col within 64
    const u16* A = (*flag) ? Abf : (const u16*)x;

    const f32x4 z = {0.f, 0.f, 0.f, 0.f};
    f32x4 acc[4][4];
    #pragma unroll
    for (int mi = 0; mi < 4; ++mi)
        #pragma unroll
        for (int ni = 0; ni < 4; ++ni) acc[mi][ni] = z;

    for (int k0 = 0; k0 < K; k0 += 64) {
        __syncthreads();                 // previous compute done reading LDS
        #pragma unroll
        for (int i = 0; i < 4; ++i) {
            const int chunk = w * 4 + i;               // wave-uniform
            const int row = chunk * 8 + lr;
            gload_lds16(&A [(size_t)(m0 + row) * K + k0 + lc], &As[chunk * 512]);
            gload_lds16(&Bt[(size_t)(n0 + row) * K + k0 + lc], &Bs[chunk * 512]);
        }
        __syncthreads();                 // compiler drains vmcnt(0) here
        #pragma unroll
        for (int kk = 0; kk < 2; ++kk) {
            bf16x8 af[4], bfr[4];
            #pragma unroll
            for (int mi = 0; mi < 4; ++mi)
                af[mi] = *(const bf16x8*)&As[(wm + mi * 16 + m16) * 64 + kk * 32 + quad * 8];
            #pragma unroll
            for (int ni = 0; ni < 4; ++ni)
                bfr[ni] = *(const bf16x8*)&Bs[(wn + ni * 16 + m16) * 64 + kk * 32 + quad * 8];
            #pragma unroll
            for (int mi = 0; mi < 4; ++mi)
                #pragma unroll
                for (int ni = 0; ni < 4; ++ni)
                    acc[mi][ni] = MFMA16(af[mi], bfr[ni], acc[mi][ni]);
        }
    }

    const int sec = n0 >> 10;  // 0=Q,1=K,2=V — uniform per block (128 | 1024)
    const float qscale = (sec == 0) ? 0.18033688011112042f : 1.0f;  // 0.125*log2e
    u16* Outp = (sec == 0) ? Ql : (sec == 1) ? Kl : Vl;
    #pragma unroll
    for (int mi = 0; mi < 4; ++mi) {
        #pragma unroll
        for (int ni = 0; ni < 4; ++ni) {
            int gn = n0 + wn + ni * 16 + m16;
            int sn = gn & 1023;
            int h = sn >> 6, d = sn & 63;
            float bv = b2f(bias[gn]);
            #pragma unroll
            for (int v = 0; v < 4; ++v) {
                int gm = m0 + wm + mi * 16 + quad * 4 + v;
                int bb = gm >> 11, tt = gm & 2047;
                u16 o = f2b((acc[mi][ni][v] + bv) * qscale);
                size_t bh = (size_t)(bb * 16 + h);
                Outp[(bh * 2048 + tt) * 64 + d] = o;
            }
        }
    }
}

// ---------------- flash attention: block = (128 q rows, one (b,h)) ---------
// Round-6 structure plus:
//  * CU-balanced qb map: 1024 blocks = exactly 4 resident/CU; CU c hosts
//    blocks {c, c+256, c+512, c+768} -> qb-groups {g, g+4, g+8, g+12}.
//    qb table {15-r, 8+r, 7-r, r} makes every CU's four groups sum to 34
//    tile-units (was 40 vs 28 under plain LPT -> occupancy decay tail).
//    bh = idx&63 untouched -> XCD affinity preserved.
//  * l computed by MFMA (accl += ones x P^T) instead of 128 serial VALU
//    adds/wave-tile: VALU was the busiest pipe (30%), MFMA at 23%.
//    C-layout: every lane's accl[0] = l(q) -> no epilogue shfl.
//  * s_setprio(1) around MFMA clusters (independent blocks -> T5 regime).
__global__ __launch_bounds__(256) void k_attn(
    u16* __restrict__ Ql, const u16* __restrict__ Kl, const u16* __restrict__ Vl)
{
    __shared__ u16 Ks[128 * 80];
    __shared__ u16 Vs[64 * 132];
    const int t = threadIdx.x;
    const int lane = t & 63, w = t >> 6;
    const int quad = lane >> 4, m16 = lane & 15;
    const int g = blockIdx.x >> 6;
    const int p = g >> 2, r = g & 3;
    const int qb = (p == 0) ? 15 - r : (p == 1) ? 8 + r : (p == 2) ? 7 - r : r;
    const int bh = blockIdx.x & 63;            // XCD affinity (64 % 8 == 0)
    const int q0 = qb * 128;

    // Q fragments for both strips, registers for the whole block
    bf16x8 fq[2][2];
    #pragma unroll
    for (int s = 0; s < 2; ++s) {
        const u16* Qp = Ql + ((size_t)bh * 2048 + q0 + s * 64 + w * 16 + m16) * 64;
        fq[s][0] = *(const bf16x8*)&Qp[quad * 8];
        fq[s][1] = *(const bf16x8*)&Qp[32 + quad * 8];
    }

    const f32x4 z = {0.f, 0.f, 0.f, 0.f};
    f32x4 acco[2][4] = {{z, z, z, z}, {z, z, z, z}};   // O^T: q=m16, d=nd*16+quad*4+v
    f32x4 accl[2] = {z, z};                            // l: every row = l(q=m16)
    s16x4 ones4;
    #pragma unroll
    for (int j = 0; j < 4; ++j) ones4[j] = (short)0x3F80;   // bf16 1.0

    const int ktmax = qb;
    const u16* Kbase = Kl + (size_t)bh * 2048 * 64;
    const u16* Vbase = Vl + (size_t)bh * 2048 * 64;

    uint4 kreg[4], vreg[4];
    #pragma unroll
    for (int i = 0; i < 4; ++i) {
        int c = t + 256 * i;
        int rr = c >> 3, col = (c & 7) * 8;
        kreg[i] = *(const uint4*)&Kbase[(size_t)rr * 64 + col];          // kt=0
        vreg[i] = *(const uint4*)&Vbase[(size_t)rr * 64 + col];          // kt=0
    }

    for (int kt = 0; kt <= ktmax; ++kt) {
        __syncthreads();
        #pragma unroll
        for (int i = 0; i < 4; ++i) {
            int c = t + 256 * i;
            int rr = c >> 3, col = (c & 7) * 8;  // rr = row (kv), col = d0
            *(uint4*)&Ks[rr * 80 + col] = kreg[i];
            union { u16 u[8]; uint4 v; } tv; tv.v = vreg[i];
            #pragma unroll
            for (int j = 0; j < 8; ++j)          // transpose into Vs[d][kv]
                Vs[(col + j) * 132 + rr] = tv.u[j];
        }
        __syncthreads();

        if (kt < ktmax) {   // prefetch next tile; overlaps compute
            #pragma unroll
            for (int i = 0; i < 4; ++i) {
                int c = t + 256 * i;
                int rr = c >> 3, col = (c & 7) * 8;
                kreg[i] = *(const uint4*)&Kbase[(size_t)((kt + 1) * 128 + rr) * 64 + col];
                vreg[i] = *(const uint4*)&Vbase[(size_t)((kt + 1) * 128 + rr) * 64 + col];
            }
        }

        const bool diag = (kt == ktmax);
        #pragma unroll
        for (int s = 0; s < 2; ++s) {
            // S^T = K Q^T  (lane: q = m16, kv = ni*16 + quad*4 + v)
            f32x4 accs[8] = {z, z, z, z, z, z, z, z};
            __builtin_amdgcn_s_setprio(1);
            #pragma unroll
            for (int kk = 0; kk < 2; ++kk)
                #pragma unroll
                for (int ni = 0; ni < 8; ++ni) {
                    bf16x8 bk = *(const bf16x8*)&Ks[(ni * 16 + m16) * 80 + kk * 32 + quad * 8];
                    accs[ni] = MFMA16(bk, fq[s][kk], accs[ni]);
                }
            __builtin_amdgcn_s_setprio(0);

            // p = exp2(s^T): pack to bf16 IN REGISTERS (B-fragment of K=16 mfma)
            s16x4 pkv[8];
            if (!diag) {
                #pragma unroll
                for (int ni = 0; ni < 8; ++ni) {
                    union { __bf16 b[4]; s16x4 sv; } pk;
                    #pragma unroll
                    for (int v = 0; v < 4; ++v)
                        pk.b[v] = (__bf16)__builtin_amdgcn_exp2f(accs[ni][v]);
                    pkv[ni] = pk.sv;
                }
            } else {
                const int qg = q0 + s * 64 + w * 16 + m16;
                #pragma unroll
                for (int ni = 0; ni < 8; ++ni) {
                    union { __bf16 b[4]; s16x4 sv; } pk;
                    #pragma unroll
                    for (int v = 0; v < 4; ++v) {
                        float sc = accs[ni][v];
                        if (kt * 128 + ni * 16 + quad * 4 + v > qg) sc = -30000.0f;
                        pk.b[v] = (__bf16)__builtin_amdgcn_exp2f(sc);
                    }
                    pkv[ni] = pk.sv;
                }
            }

            // O^T += V^T P^T ; l += ones x P^T   (all on the matrix pipe)
            __builtin_amdgcn_s_setprio(1);
            #pragma unroll
            for (int ni = 0; ni < 8; ++ni) {
                #pragma unroll
                for (int nd = 0; nd < 4; ++nd) {
                    s16x4 va = *(const s16x4*)&Vs[(nd * 16 + m16) * 132 + ni * 16 + quad * 4];
                    acco[s][nd] = MFMA1K(va, pkv[ni], acco[s][nd]);
                }
                accl[s] = MFMA1K(ones4, pkv[ni], accl[s]);
            }
            __builtin_amdgcn_s_setprio(0);
        }
    }

    // write O back into Ql ([bh][t][64]): lane owns row q = qg, 4 consecutive d
    #pragma unroll
    for (int s = 0; s < 2; ++s) {
        const int qg = q0 + s * 64 + w * 16 + m16;
        const float inv = 1.0f / fmaxf(accl[s][0], 1e-30f);
        u16* Orow = &Ql[((size_t)bh * 2048 + qg) * 64];
        #pragma unroll
        for (int nd = 0; nd < 4; ++nd) {
            union { u16 u[4]; uint2 uu; } o;
            #pragma unroll
            for (int v = 0; v < 4; ++v) o.u[v] = f2b(acco[s][nd][v] * inv);
            *(uint2*)&Orow[nd * 16 + quad * 4] = o.uu;
        }
    }
}

// ------- proj GEMM: Y (in Ql layout [bh][t][64]) x WpT[1024,1024]^T + bias -
__global__ __launch_bounds__(256) void k_gemm_proj(
    const u16* __restrict__ Yl, const u16* __restrict__ Bt, const u16* __restrict__ bias,
    const int* __restrict__ flag, void* __restrict__ Out)
{
    constexpr int K = 1024;
    __shared__ __align__(16) u16 As[128 * 64];
    __shared__ __align__(16) u16 Bs[128 * 64];
    const int f32m = *flag;
    const int t = threadIdx.x;
    const int lane = t & 63, w = t >> 6;
    const int quad = lane >> 4, m16 = lane & 15;
    const int wm = (w >> 1) * 64, wn = (w & 1) * 64;
    const int m0 = blockIdx.x * 128, n0 = blockIdx.y * 128;
    const int bb = m0 >> 11, t0 = m0 & 2047;   // block-uniform (128 | 2048)
    const int lr = lane >> 3;
    const int lc = (lane & 7) * 8;

    const f32x4 z = {0.f, 0.f, 0.f, 0.f};
    f32x4 acc[4][4];
    #pragma unroll
    for (int mi = 0; mi < 4; ++mi)
        #pragma unroll
        for (int ni = 0; ni < 4; ++ni) acc[mi][ni] = z;

    for (int k0 = 0; k0 < K; k0 += 64) {
        const int h = k0 >> 6;
        const u16* Abase = Yl + ((size_t)(bb * 16 + h) * 2048 + t0) * 64;
        __syncthreads();
        #pragma unroll
        for (int i = 0; i < 4; ++i) {
            const int chunk = w * 4 + i;               // wave-uniform
            gload_lds16(&Abase[chunk * 512 + lane * 8], &As[chunk * 512]);
            gload_lds16(&Bt[(size_t)(n0 + chunk * 8 + lr) * K + k0 + lc], &Bs[chunk * 512]);
        }
        __syncthreads();
        #pragma unroll
        for (int kk = 0; kk < 2; ++kk) {
            bf16x8 af[4], bfr[4];
            #pragma unroll
            for (int mi = 0; mi < 4; ++mi)
                af[mi] = *(const bf16x8*)&As[(wm + mi * 16 + m16) * 64 + kk * 32 + quad * 8];
            #pragma unroll
            for (int ni = 0; ni < 4; ++ni)
                bfr[ni] = *(const bf16x8*)&Bs[(wn + ni * 16 + m16) * 64 + kk * 32 + quad * 8];
            #pragma unroll
            for (int mi = 0; mi < 4; ++mi)
                #pragma unroll
                for (int ni = 0; ni < 4; ++ni)
                    acc[mi][ni] = MFMA16(af[mi], bfr[ni], acc[mi][ni]);
        }
    }

    #pragma unroll
    for (int mi = 0; mi < 4; ++mi) {
        #pragma unroll
        for (int ni = 0; ni < 4; ++ni) {
            int gn = n0 + wn + ni * 16 + m16;
            float bv = b2f(bias[gn]);
            #pragma unroll
            for (int v = 0; v < 4; ++v) {
                int gm = m0 + wm + mi * 16 + quad * 4 + v;
                float val = acc[mi][ni][v] + bv;
                if (f32m) ((float*)Out)[(size_t)gm * 1024 + gn] = val;
                else      ((u16*)Out)[(size_t)gm * 1024 + gn] = f2b(val);
            }
        }
    }
}

extern "C" void kernel_launch(void* const* d_in, const int* in_sizes, int n_in,
                              void* d_out, int out_size, void* d_ws, size_t ws_size,
                              hipStream_t stream)
{
    (void)in_sizes; (void)n_in; (void)out_size; (void)ws_size;
    const void* x  = d_in[0];   // [8192,1024]  f32 or bf16
    const void* Wa = d_in[1];   // [1024,3072]
    const void* ba = d_in[2];   // [3072]
    const void* Wp = d_in[3];   // [1024,1024]
    const void* bp = d_in[4];   // [1024]
    char* ws = (char*)d_ws;

    // ws: Q/O 16M @0 | K 16M @16M | V(row-major) 16M @32M | WpT 2M @48M | misc @50M
    u16* Ql  = (u16*)(ws + 0);
    u16* Kl  = (u16*)(ws + 16777216);
    u16* Vl  = (u16*)(ws + 33554432);
    u16* WpT = (u16*)(ws + 50331648);
    int* flag = (int*)(ws + 52428800);
    u16* bpc  = (u16*)(ws + 52428800 + 256);
    u16* bac  = (u16*)(ws + 52428800 + 256 + 2048);
    // d_out doubles as scratch until proj:
    //   WaT 6M @0 | Abf (bf16 x) 16M @6M (written only in f32 mode, where
    //   out_size = 33.5M; in bf16 mode Abf is never touched and A = x).
    u16* WaT = (u16*)d_out;
    u16* Abf = (u16*)((char*)d_out + 6291456);

    k_prep<<<5121, 256, 0, stream>>>((const u16*)x, Wa, ba, Wp, bp,
                                     WaT, WpT, Abf, bac, bpc, flag);
    k_gemm_qkv<<<dim3(64, 24), 256, 0, stream>>>(x, Abf, WaT, bac, flag, Ql, Kl, Vl);
    k_attn<<<1024, 256, 0, stream>>>(Ql, Kl, Vl);
    k_gemm_proj<<<dim3(64, 8), 256, 0, stream>>>(Ql, WpT, bpc, flag, d_out);
}

// Round 8
// 276.780 us; speedup vs baseline: 1.2546x; 1.0443x over previous
//
#include <hip/hip_runtime.h>

typedef unsigned short u16;
typedef unsigned int u32;
typedef __bf16 bf16x8 __attribute__((ext_vector_type(8)));
typedef short s16x4 __attribute__((ext_vector_type(4)));
typedef float f32x4 __attribute__((ext_vector_type(4)));

#define MFMA16(a,b,c) __builtin_amdgcn_mfma_f32_16x16x32_bf16((a),(b),(c),0,0,0)

// K=16 bf16 MFMA (v_mfma_f32_16x16x16_bf16): A/B = 4 bf16 (2 VGPR), C/D = 4 f32.
#if defined(__has_builtin)
#if __has_builtin(__builtin_amdgcn_mfma_f32_16x16x16bf16_1k)
#define MFMA1K(a,b,c) __builtin_amdgcn_mfma_f32_16x16x16bf16_1k((a),(b),(c),0,0,0)
#endif
#endif
#ifndef MFMA1K
__device__ __forceinline__ f32x4 mfma1k_asm(s16x4 a, s16x4 b, f32x4 c) {
    f32x4 d;
    asm volatile("v_mfma_f32_16x16x16_bf16 %0, %1, %2, %3"
                 : "=v"(d) : "v"(a), "v"(b), "0"(c));
    return d;
}
#define MFMA1K(a,b,c) mfma1k_asm((a),(b),(c))
#endif

__device__ __forceinline__ float b2f(u16 u) {
    u32 v = ((u32)u) << 16;
    return __builtin_bit_cast(float, v);
}
__device__ __forceinline__ u16 f2b(float f) {
    u32 u = __builtin_bit_cast(u32, f);
    u = u + 0x7FFFu + ((u >> 16) & 1u);   // RNE
    return (u16)(u >> 16);
}

// async global->LDS, 16B per lane. LDS dest is wave-uniform base + lane*16.
__device__ __forceinline__ void gload_lds16(const u16* g, u16* l) {
    __builtin_amdgcn_global_load_lds(
        (__attribute__((address_space(1))) void*)g,
        (__attribute__((address_space(3))) void*)l, 16, 0, 0);
}

// load 8 contiguous elements at element-offset `off`, as 8 bf16 (uint4).
__device__ __forceinline__ uint4 load8_bf16(const void* base, size_t off, int f32m) {
    if (f32m) {
        const float* p = (const float*)base + off;
        float4 a = *(const float4*)p;
        float4 b = *(const float4*)(p + 4);
        union { u16 u[8]; uint4 v; } t;
        t.u[0] = f2b(a.x); t.u[1] = f2b(a.y); t.u[2] = f2b(a.z); t.u[3] = f2b(a.w);
        t.u[4] = f2b(b.x); t.u[5] = f2b(b.y); t.u[6] = f2b(b.z); t.u[7] = f2b(b.w);
        return t.v;
    }
    return *(const uint4*)((const u16*)base + off);
}

// ---- per-block deterministic dtype vote (identical result in every block)
__device__ __forceinline__ int detect_f32(const u16* __restrict__ x) {
    __shared__ int cnt;
    if (threadIdx.x == 0) cnt = 0;
    __syncthreads();
    int my = ((x[2 * (threadIdx.x * 128)] >> 7) & 0xFF) >= 0x90;
    unsigned long long b = __ballot(my);
    if ((threadIdx.x & 63) == 0) atomicAdd(&cnt, (int)__popcll(b));
    __syncthreads();
    return cnt > 32;
}

// ---- transpose+convert tile: src[R][Cc] -> dst[Cc][R] bf16, 64x64 tile ----
__device__ __forceinline__ void transpose_tile(
    const void* __restrict__ src, u16* __restrict__ dst, int R, int Cc,
    int f32m, int bx, int by)
{
    __shared__ u16 tile[64 * 72];
    const int t = threadIdx.x;
    const int c0 = bx * 64, r0 = by * 64;
    #pragma unroll
    for (int i = 0; i < 2; ++i) {
        int ch = t + 256 * i;            // 512 chunks of 8
        int r = ch >> 3, c8 = (ch & 7) * 8;
        *(uint4*)&tile[r * 72 + c8] =
            load8_bf16(src, (size_t)(r0 + r) * Cc + c0 + c8, f32m);
    }
    __syncthreads();
    #pragma unroll
    for (int i = 0; i < 2; ++i) {
        int ch = t + 256 * i;
        int r = ch >> 3, c8 = (ch & 7) * 8;
        union { u16 u[8]; uint4 v; } tmp;
        #pragma unroll
        for (int j = 0; j < 8; ++j) tmp.u[j] = tile[(c8 + j) * 72 + r];
        *(uint4*)&dst[(size_t)(c0 + r) * R + r0 + c8] = tmp.v;
    }
}

// ---- fused preprocessing (unchanged from round 7) ----
__global__ __launch_bounds__(256) void k_prep(
    const u16* __restrict__ x, const void* __restrict__ Wa,
    const void* __restrict__ ba, const void* __restrict__ Wp,
    const void* __restrict__ bp,
    u16* __restrict__ WaT, u16* __restrict__ WpT, u16* __restrict__ Abf,
    u16* __restrict__ bac, u16* __restrict__ bpc, int* __restrict__ flag)
{
    const int f32m = detect_f32(x);
    int task = blockIdx.x;
    if (task < 768) {
        transpose_tile(Wa, WaT, 1024, 3072, f32m, task % 48, task / 48);
        return;
    }
    task -= 768;
    if (task < 256) {
        transpose_tile(Wp, WpT, 1024, 1024, f32m, task % 16, task / 16);
        return;
    }
    task -= 256;
    if (task < 4096) {
        if (!f32m) return;
        size_t i = ((size_t)task * 256 + threadIdx.x) * 8;
        const float* xf = (const float*)x;
        float4 a = *(const float4*)(xf + i);
        float4 b = *(const float4*)(xf + i + 4);
        union { u16 u[8]; uint4 v; } t;
        t.u[0] = f2b(a.x); t.u[1] = f2b(a.y); t.u[2] = f2b(a.z); t.u[3] = f2b(a.w);
        t.u[4] = f2b(b.x); t.u[5] = f2b(b.y); t.u[6] = f2b(b.z); t.u[7] = f2b(b.w);
        *(uint4*)(Abf + i) = t.v;
        return;
    }
    const int t = threadIdx.x;
    #pragma unroll
    for (int j = 0; j < 12; ++j) {
        int i = t + 256 * j;
        if (i < 3072) bac[i] = f32m ? f2b(((const float*)ba)[i]) : ((const u16*)ba)[i];
    }
    #pragma unroll
    for (int j = 0; j < 4; ++j) {
        int i = t + 256 * j;
        if (i < 1024) bpc[i] = f32m ? f2b(((const float*)bp)[i]) : ((const u16*)bp)[i];
    }
    if (t == 0) *flag = f32m;
}

// ======================= 8-phase 256-tile GEMM machinery ====================
// LDS granule swizzle (16B granules, 8 granules = one 64-elem bf16 row):
//   logical (row r, slot s) lives at LDS granule (r<<3) | (s ^ (r&7)).
// global_load_lds writes linearly -> stage granule g from GLOBAL granule
//   (r, (g&7) ^ (r&7)): both-sides-or-neither (the source permutation and
//   the read permutation are the same involution).
// Reads: 16 lanes at same slot, 16 consecutive rows -> 8 distinct bank
// quads x 2-way (free) instead of 8-16-way serialize.

// stage one 256x64 A-tile + 256x64 B-tile (8 vmcnt ops/thread, A first)
__device__ __forceinline__ void stage8(const u16* __restrict__ Asrc,
                                       const u16* __restrict__ Bsrc,
                                       u16* Asb, u16* Bsb, int wbase, int lane)
{
    #pragma unroll
    for (int i = 0; i < 4; ++i) {
        int gbase = wbase + 512 * i;
        int g = gbase | lane;
        int r = g >> 3, u = (g & 7) ^ (r & 7);
        gload_lds16(Asrc + (size_t)r * 1024 + u * 8, Asb + gbase * 8);
    }
    #pragma unroll
    for (int i = 0; i < 4; ++i) {
        int gbase = wbase + 512 * i;
        int g = gbase | lane;
        int r = g >> 3, u = (g & 7) ^ (r & 7);
        gload_lds16(Bsrc + (size_t)r * 1024 + u * 8, Bsb + gbase * 8);
    }
}

// stage one contiguous-[256][64] A-tile + 128x64 B-tile (6 vmcnt ops/thread)
__device__ __forceinline__ void stage6(const u16* __restrict__ Asrc,
                                       const u16* __restrict__ Bsrc,
                                       u16* Asb, u16* Bsb, int wbase, int lane)
{
    #pragma unroll
    for (int i = 0; i < 4; ++i) {
        int gbase = wbase + 512 * i;
        int g = gbase | lane;
        int gg = (g & ~7) | ((g & 7) ^ ((g >> 3) & 7));
        gload_lds16(Asrc + gg * 8, Asb + gbase * 8);
    }
    #pragma unroll
    for (int i = 0; i < 2; ++i) {
        int gbase = wbase + 512 * i;
        int g = gbase | lane;
        int r = g >> 3, u = (g & 7) ^ (r & 7);
        gload_lds16(Bsrc + (size_t)r * 1024 + u * 8, Bsb + gbase * 8);
    }
}

__device__ __forceinline__ const u16* frag_ptr(const u16* base, int R, int sl) {
    int gr = (R << 3) | (sl ^ (R & 7));
    return base + gr * 8;
}

// ---------------- QKV GEMM: A[8192,1024] x Bt[3072,1024]^T + bias ----------
// 256x256 tile, BK=64, 8 waves (2M x 4N), 128 KB double-buffered swizzled
// LDS, tiles staged 2 ahead via global_load_lds, counted vmcnt(8) (never 0
// in-loop), raw s_barrier + sched_barrier(0) fences, setprio around MFMA.
__global__ __launch_bounds__(512, 2) void k_gemm_qkv(
    const void* __restrict__ x, const u16* __restrict__ Abf,
    const u16* __restrict__ Bt, const u16* __restrict__ bias,
    const int* __restrict__ flag,
    u16* __restrict__ Ql, u16* __restrict__ Kl, u16* __restrict__ Vl)
{
    __shared__ __align__(16) u16 As[2][16384];   // 64 KB
    __shared__ __align__(16) u16 Bs[2][16384];   // 64 KB
    const int t = threadIdx.x;
    const int lane = t & 63, w = t >> 6;
    const int wbase = t & ~63;                   // w*64
    const int quad = lane >> 4, m16 = lane & 15;
    const int wr = w >> 2, wc = w & 3;           // 2 x 4 wave grid
    const int m0 = blockIdx.x * 256, n0 = blockIdx.y * 256;
    const u16* A = (*flag) ? Abf : (const u16*)x;

    const u16* Atile = A + (size_t)m0 * 1024;
    const u16* Btile = Bt + (size_t)n0 * 1024;

    const f32x4 z = {0.f, 0.f, 0.f, 0.f};
    f32x4 acc[8][4];
    #pragma unroll
    for (int mi = 0; mi < 8; ++mi)
        #pragma unroll
        for (int ni = 0; ni < 4; ++ni) acc[mi][ni] = z;

    // prologue: tiles 0,1 in flight; wait tile 0 (counted)
    stage8(Atile,      Btile,      &As[0][0], &Bs[0][0], wbase, lane);
    stage8(Atile + 64, Btile + 64, &As[1][0], &Bs[1][0], wbase, lane);
    __builtin_amdgcn_sched_barrier(0);
    asm volatile("s_waitcnt vmcnt(8)" ::: "memory");
    __builtin_amdgcn_s_barrier();
    __builtin_amdgcn_sched_barrier(0);

    for (int kt = 0; kt < 16; ++kt) {
        const u16* Asb = &As[kt & 1][0];
        const u16* Bsb = &Bs[kt & 1][0];

        // B fragments once per K-tile (wave's 64-col quarter)
        bf16x8 bfr[4][2];
        #pragma unroll
        for (int ni = 0; ni < 4; ++ni)
            #pragma unroll
            for (int kk = 0; kk < 2; ++kk)
                bfr[ni][kk] = *(const bf16x8*)frag_ptr(Bsb, wc * 64 + ni * 16 + m16, kk * 4 + quad);

        // 4 phases x 16 MFMA
        #pragma unroll
        for (int ph = 0; ph < 4; ++ph) {
            bf16x8 af[2][2];
            #pragma unroll
            for (int m2 = 0; m2 < 2; ++m2)
                #pragma unroll
                for (int kk = 0; kk < 2; ++kk)
                    af[m2][kk] = *(const bf16x8*)frag_ptr(
                        Asb, wr * 128 + (ph * 2 + m2) * 16 + m16, kk * 4 + quad);
            __builtin_amdgcn_s_setprio(1);
            #pragma unroll
            for (int m2 = 0; m2 < 2; ++m2)
                #pragma unroll
                for (int ni = 0; ni < 4; ++ni) {
                    acc[ph * 2 + m2][ni] = MFMA16(af[m2][0], bfr[ni][0], acc[ph * 2 + m2][ni]);
                    acc[ph * 2 + m2][ni] = MFMA16(af[m2][1], bfr[ni][1], acc[ph * 2 + m2][ni]);
                }
            __builtin_amdgcn_s_setprio(0);
        }

        __builtin_amdgcn_sched_barrier(0);
        __builtin_amdgcn_s_barrier();            // bar1: all reads of this buf done
        if (kt < 14)
            stage8(Atile + (kt + 2) * 64, Btile + (kt + 2) * 64,
                   (u16*)Asb, (u16*)Bsb, wbase, lane);
        __builtin_amdgcn_sched_barrier(0);
        if (kt < 14) asm volatile("s_waitcnt vmcnt(8)" ::: "memory");  // tile kt+1 landed
        else         asm volatile("s_waitcnt vmcnt(0)" ::: "memory");
        __builtin_amdgcn_s_barrier();            // bar2
        __builtin_amdgcn_sched_barrier(0);
    }

    // epilogue: scatter Q,K,V coalesced [BH][T][64]
    const int sec = n0 >> 10;  // uniform per block (256 | 1024)
    const float qscale = (sec == 0) ? 0.18033688011112042f : 1.0f;  // 0.125*log2e
    u16* Outp = (sec == 0) ? Ql : (sec == 1) ? Kl : Vl;
    #pragma unroll
    for (int mi = 0; mi < 8; ++mi) {
        #pragma unroll
        for (int ni = 0; ni < 4; ++ni) {
            int gn = n0 + wc * 64 + ni * 16 + m16;
            int sn = gn & 1023;
            int h = sn >> 6, d = sn & 63;
            float bv = b2f(bias[gn]);
            #pragma unroll
            for (int v = 0; v < 4; ++v) {
                int gm = m0 + wr * 128 + mi * 16 + quad * 4 + v;
                int bb = gm >> 11, tt = gm & 2047;
                u16 o = f2b((acc[mi][ni][v] + bv) * qscale);
                size_t bh = (size_t)(bb * 16 + h);
                Outp[(bh * 2048 + tt) * 64 + d] = o;
            }
        }
    }
}

// ---------------- flash attention (unchanged from round 7) -----------------
__global__ __launch_bounds__(256) void k_attn(
    u16* __restrict__ Ql, const u16* __restrict__ Kl, const u16* __restrict__ Vl)
{
    __shared__ u16 Ks[128 * 80];
    __shared__ u16 Vs[64 * 132];
    const int t = threadIdx.x;
    const int lane = t & 63, w = t >> 6;
    const int quad = lane >> 4, m16 = lane & 15;
    const int g = blockIdx.x >> 6;
    const int p = g >> 2, r = g & 3;
    const int qb = (p == 0) ? 15 - r : (p == 1) ? 8 + r : (p == 2) ? 7 - r : r;
    const int bh = blockIdx.x & 63;            // XCD affinity (64 % 8 == 0)
    const int q0 = qb * 128;

    bf16x8 fq[2][2];
    #pragma unroll
    for (int s = 0; s < 2; ++s) {
        const u16* Qp = Ql + ((size_t)bh * 2048 + q0 + s * 64 + w * 16 + m16) * 64;
        fq[s][0] = *(const bf16x8*)&Qp[quad * 8];
        fq[s][1] = *(const bf16x8*)&Qp[32 + quad * 8];
    }

    const f32x4 z = {0.f, 0.f, 0.f, 0.f};
    f32x4 acco[2][4] = {{z, z, z, z}, {z, z, z, z}};   // O^T: q=m16, d=nd*16+quad*4+v
    f32x4 accl[2] = {z, z};                            // l: every row = l(q=m16)
    s16x4 ones4;
    #pragma unroll
    for (int j = 0; j < 4; ++j) ones4[j] = (short)0x3F80;   // bf16 1.0

    const int ktmax = qb;
    const u16* Kbase = Kl + (size_t)bh * 2048 * 64;
    const u16* Vbase = Vl + (size_t)bh * 2048 * 64;

    uint4 kreg[4], vreg[4];
    #pragma unroll
    for (int i = 0; i < 4; ++i) {
        int c = t + 256 * i;
        int rr = c >> 3, col = (c & 7) * 8;
        kreg[i] = *(const uint4*)&Kbase[(size_t)rr * 64 + col];
        vreg[i] = *(const uint4*)&Vbase[(size_t)rr * 64 + col];
    }

    for (int kt = 0; kt <= ktmax; ++kt) {
        __syncthreads();
        #pragma unroll
        for (int i = 0; i < 4; ++i) {
            int c = t + 256 * i;
            int rr = c >> 3, col = (c & 7) * 8;
            *(uint4*)&Ks[rr * 80 + col] = kreg[i];
            union { u16 u[8]; uint4 v; } tv; tv.v = vreg[i];
            #pragma unroll
            for (int j = 0; j < 8; ++j)
                Vs[(col + j) * 132 + rr] = tv.u[j];
        }
        __syncthreads();

        if (kt < ktmax) {
            #pragma unroll
            for (int i = 0; i < 4; ++i) {
                int c = t + 256 * i;
                int rr = c >> 3, col = (c & 7) * 8;
                kreg[i] = *(const uint4*)&Kbase[(size_t)((kt + 1) * 128 + rr) * 64 + col];
                vreg[i] = *(const uint4*)&Vbase[(size_t)((kt + 1) * 128 + rr) * 64 + col];
            }
        }

        const bool diag = (kt == ktmax);
        #pragma unroll
        for (int s = 0; s < 2; ++s) {
            f32x4 accs[8] = {z, z, z, z, z, z, z, z};
            __builtin_amdgcn_s_setprio(1);
            #pragma unroll
            for (int kk = 0; kk < 2; ++kk)
                #pragma unroll
                for (int ni = 0; ni < 8; ++ni) {
                    bf16x8 bk = *(const bf16x8*)&Ks[(ni * 16 + m16) * 80 + kk * 32 + quad * 8];
                    accs[ni] = MFMA16(bk, fq[s][kk], accs[ni]);
                }
            __builtin_amdgcn_s_setprio(0);

            s16x4 pkv[8];
            if (!diag) {
                #pragma unroll
                for (int ni = 0; ni < 8; ++ni) {
                    union { __bf16 b[4]; s16x4 sv; } pk;
                    #pragma unroll
                    for (int v = 0; v < 4; ++v)
                        pk.b[v] = (__bf16)__builtin_amdgcn_exp2f(accs[ni][v]);
                    pkv[ni] = pk.sv;
                }
            } else {
                const int qg = q0 + s * 64 + w * 16 + m16;
                #pragma unroll
                for (int ni = 0; ni < 8; ++ni) {
                    union { __bf16 b[4]; s16x4 sv; } pk;
                    #pragma unroll
                    for (int v = 0; v < 4; ++v) {
                        float sc = accs[ni][v];
                        if (kt * 128 + ni * 16 + quad * 4 + v > qg) sc = -30000.0f;
                        pk.b[v] = (__bf16)__builtin_amdgcn_exp2f(sc);
                    }
                    pkv[ni] = pk.sv;
                }
            }

            __builtin_amdgcn_s_setprio(1);
            #pragma unroll
            for (int ni = 0; ni < 8; ++ni) {
                #pragma unroll
                for (int nd = 0; nd < 4; ++nd) {
                    s16x4 va = *(const s16x4*)&Vs[(nd * 16 + m16) * 132 + ni * 16 + quad * 4];
                    acco[s][nd] = MFMA1K(va, pkv[ni], acco[s][nd]);
                }
                accl[s] = MFMA1K(ones4, pkv[ni], accl[s]);
            }
            __builtin_amdgcn_s_setprio(0);
        }
    }

    #pragma unroll
    for (int s = 0; s < 2; ++s) {
        const int qg = q0 + s * 64 + w * 16 + m16;
        const float inv = 1.0f / fmaxf(accl[s][0], 1e-30f);
        u16* Orow = &Ql[((size_t)bh * 2048 + qg) * 64];
        #pragma unroll
        for (int nd = 0; nd < 4; ++nd) {
            union { u16 u[4]; uint2 uu; } o;
            #pragma unroll
            for (int v = 0; v < 4; ++v) o.u[v] = f2b(acco[s][nd][v] * inv);
            *(uint2*)&Orow[nd * 16 + quad * 4] = o.uu;
        }
    }
}

// ------- proj GEMM: Y (in Ql layout [bh][t][64]) x WpT[1024,1024]^T + bias -
// Same 8-phase skeleton at 256x128 (grid 32x8 = 256 blocks = exactly 1/CU).
// Per K-tile the A chunk is a CONTIGUOUS [256][64] block of Yl (h = kt).
__global__ __launch_bounds__(512, 2) void k_gemm_proj(
    const u16* __restrict__ Yl, const u16* __restrict__ Bt, const u16* __restrict__ bias,
    const int* __restrict__ flag, void* __restrict__ Out)
{
    __shared__ __align__(16) u16 As[2][16384];   // 64 KB
    __shared__ __align__(16) u16 Bs[2][8192];    // 32 KB
    const int f32m = *flag;
    const int t = threadIdx.x;
    const int lane = t & 63, w = t >> 6;
    const int wbase = t & ~63;
    const int quad = lane >> 4, m16 = lane & 15;
    const int wr = w >> 2, wc = w & 3;           // 2 x 4 wave grid (per-wave 128x32)
    const int m0 = blockIdx.x * 256, n0 = blockIdx.y * 128;
    const int bb = m0 >> 11, t0 = m0 & 2047;     // block-uniform (256 | 2048)

    const u16* Btile = Bt + (size_t)n0 * 1024;
    #define ABASE(KT) (Yl + ((size_t)(bb * 16 + (KT)) * 2048 + t0) * 64)

    const f32x4 z = {0.f, 0.f, 0.f, 0.f};
    f32x4 acc[8][2];
    #pragma unroll
    for (int mi = 0; mi < 8; ++mi)
        #pragma unroll
        for (int ni = 0; ni < 2; ++ni) acc[mi][ni] = z;

    stage6(ABASE(0), Btile,      &As[0][0], &Bs[0][0], wbase, lane);
    stage6(ABASE(1), Btile + 64, &As[1][0], &Bs[1][0], wbase, lane);
    __builtin_amdgcn_sched_barrier(0);
    asm volatile("s_waitcnt vmcnt(6)" ::: "memory");
    __builtin_amdgcn_s_barrier();
    __builtin_amdgcn_sched_barrier(0);

    for (int kt = 0; kt < 16; ++kt) {
        const u16* Asb = &As[kt & 1][0];
        const u16* Bsb = &Bs[kt & 1][0];

        bf16x8 bfr[2][2];
        #pragma unroll
        for (int ni = 0; ni < 2; ++ni)
            #pragma unroll
            for (int kk = 0; kk < 2; ++kk)
                bfr[ni][kk] = *(const bf16x8*)frag_ptr(Bsb, wc * 32 + ni * 16 + m16, kk * 4 + quad);

        #pragma unroll
        for (int ph = 0; ph < 4; ++ph) {
            bf16x8 af[2][2];
            #pragma unroll
            for (int m2 = 0; m2 < 2; ++m2)
                #pragma unroll
                for (int kk = 0; kk < 2; ++kk)
                    af[m2][kk] = *(const bf16x8*)frag_ptr(
                        Asb, wr * 128 + (ph * 2 + m2) * 16 + m16, kk * 4 + quad);
            __builtin_amdgcn_s_setprio(1);
            #pragma unroll
            for (int m2 = 0; m2 < 2; ++m2)
                #pragma unroll
                for (int ni = 0; ni < 2; ++ni) {
                    acc[ph * 2 + m2][ni] = MFMA16(af[m2][0], bfr[ni][0], acc[ph * 2 + m2][ni]);
                    acc[ph * 2 + m2][ni] = MFMA16(af[m2][1], bfr[ni][1], acc[ph * 2 + m2][ni]);
                }
            __builtin_amdgcn_s_setprio(0);
        }

        __builtin_amdgcn_sched_barrier(0);
        __builtin_amdgcn_s_barrier();            // bar1
        if (kt < 14)
            stage6(ABASE(kt + 2), Btile + (kt + 2) * 64,
                   (u16*)Asb, (u16*)Bsb, wbase, lane);
        __builtin_amdgcn_sched_barrier(0);
        if (kt < 14) asm volatile("s_waitcnt vmcnt(6)" ::: "memory");
        else         asm volatile("s_waitcnt vmcnt(0)" ::: "memory");
        __builtin_amdgcn_s_barrier();            // bar2
        __builtin_amdgcn_sched_barrier(0);
    }
    #undef ABASE

    #pragma unroll
    for (int mi = 0; mi < 8; ++mi) {
        #pragma unroll
        for (int ni = 0; ni < 2; ++ni) {
            int gn = n0 + wc * 32 + ni * 16 + m16;
            float bv = b2f(bias[gn]);
            #pragma unroll
            for (int v = 0; v < 4; ++v) {
                int gm = m0 + wr * 128 + mi * 16 + quad * 4 + v;
                float val = acc[mi][ni][v] + bv;
                if (f32m) ((float*)Out)[(size_t)gm * 1024 + gn] = val;
                else      ((u16*)Out)[(size_t)gm * 1024 + gn] = f2b(val);
            }
        }
    }
}

extern "C" void kernel_launch(void* const* d_in, const int* in_sizes, int n_in,
                              void* d_out, int out_size, void* d_ws, size_t ws_size,
                              hipStream_t stream)
{
    (void)in_sizes; (void)n_in; (void)out_size; (void)ws_size;
    const void* x  = d_in[0];   // [8192,1024]  f32 or bf16
    const void* Wa = d_in[1];   // [1024,3072]
    const void* ba = d_in[2];   // [3072]
    const void* Wp = d_in[3];   // [1024,1024]
    const void* bp = d_in[4];   // [1024]
    char* ws = (char*)d_ws;

    // ws: Q/O 16M @0 | K 16M @16M | V(row-major) 16M @32M | WpT 2M @48M | misc @50M
    u16* Ql  = (u16*)(ws + 0);
    u16* Kl  = (u16*)(ws + 16777216);
    u16* Vl  = (u16*)(ws + 33554432);
    u16* WpT = (u16*)(ws + 50331648);
    int* flag = (int*)(ws + 52428800);
    u16* bpc  = (u16*)(ws + 52428800 + 256);
    u16* bac  = (u16*)(ws + 52428800 + 256 + 2048);
    // d_out doubles as scratch until proj: WaT 6M @0 | Abf 16M @6M
    u16* WaT = (u16*)d_out;
    u16* Abf = (u16*)((char*)d_out + 6291456);

    k_prep<<<5121, 256, 0, stream>>>((const u16*)x, Wa, ba, Wp, bp,
                                     WaT, WpT, Abf, bac, bpc, flag);
    k_gemm_qkv<<<dim3(32, 12), 512, 0, stream>>>(x, Abf, WaT, bac, flag, Ql, Kl, Vl);
    k_attn<<<1024, 256, 0, stream>>>(Ql, Kl, Vl);
    k_gemm_proj<<<dim3(32, 8), 512, 0, stream>>>(Ql, WpT, bpc, flag, d_out);
}